// Round 2
// baseline (403.163 us; speedup 1.0000x reference)
//
#include <hip/hip_runtime.h>
#include <hip/hip_bf16.h>

// ScalarQLinear via int8 MFMA, round 7:
//   R6 post-mortem: 8-phase 256^2 port regressed (127->143us, MfmaUtil 42%).
//   Cause: 16 barriers/2-K-tiles vs R5's 4, and 1 block/CU (lost cross-block
//   overlap). i8 stages half the bytes of bf16, so the drain the 8-phase
//   hides is smaller than the barrier tax it adds.
//   R7: T3-minimum dbuf at R5 geometry -- the surgical fix for R5's real
//   stall (vmcnt(0) drain immediately after STAGE issue):
//   - BK=64, LDS A[2][8K]+B[2][16K]=48KB -> still 2 blocks/CU (8 waves).
//   - Per K-step: STAGE next tile -> buf^1 FIRST, compute cur from buf,
//     THEN __syncthreads (drain is late: ~1300cy of MFMA covers HBM latency).
//   - ONE barrier per K-step (R5 had two).
//   - setprio(1) around MFMA cluster (2 independent blocks/CU = role split).
//   - Swizzle math identical to R6 (verified: 0 conflicts, passed).
//   Quantize kernel byte-identical to R5.

typedef int int32x4 __attribute__((ext_vector_type(4)));

#define MDIM 8192
#define NDIM 4096
#define KDIM 4096

__device__ __forceinline__ void async_copy16(const void* g, void* l) {
  __builtin_amdgcn_global_load_lds(
      (const __attribute__((address_space(1))) void*)g,
      (__attribute__((address_space(3))) void*)l, 16, 0, 0);
}

__device__ __forceinline__ unsigned pack4(float a, float b, float c, float d) {
  return ((unsigned)((int)a & 0xff)) | ((unsigned)((int)b & 0xff) << 8) |
         ((unsigned)((int)c & 0xff) << 16) | ((unsigned)((int)d & 0xff) << 24);
}

// --- K1: fused quantizers. Blocks [0,4096): w rows; [4096,12288): x rows. ---
__global__ __launch_bounds__(256) void quantize_all(
    const float* __restrict__ w, const float* __restrict__ x,
    unsigned* __restrict__ qw, unsigned* __restrict__ qx,
    float* __restrict__ scale, float* __restrict__ sx) {
  const int t = threadIdx.x;
  __shared__ float wred[4];
  if (blockIdx.x < NDIM) {
    const int row = blockIdx.x;
    const float4* wr = (const float4*)(w + (size_t)row * KDIM);
    float4 v[4];
    float ss = 0.f;
#pragma unroll
    for (int i = 0; i < 4; ++i) {
      v[i] = wr[t + 256 * i];
      ss += v[i].x * v[i].x + v[i].y * v[i].y + v[i].z * v[i].z + v[i].w * v[i].w;
    }
#pragma unroll
    for (int m = 32; m >= 1; m >>= 1) ss += __shfl_xor(ss, m, 64);
    if ((t & 63) == 0) wred[t >> 6] = ss;
    __syncthreads();
    const float safe = fmaxf(sqrtf(wred[0] + wred[1] + wred[2] + wred[3]), 1e-8f);
    unsigned* qr = qw + (size_t)row * (KDIM / 4);
#pragma unroll
    for (int i = 0; i < 4; ++i) {
      float q0 = fminf(fmaxf(rintf(v[i].x / safe * 60.0f), -8.f), 7.f);
      float q1 = fminf(fmaxf(rintf(v[i].y / safe * 60.0f), -8.f), 7.f);
      float q2 = fminf(fmaxf(rintf(v[i].z / safe * 60.0f), -8.f), 7.f);
      float q3 = fminf(fmaxf(rintf(v[i].w / safe * 60.0f), -8.f), 7.f);
      qr[t + 256 * i] = pack4(q0, q1, q2, q3);
    }
    if (t == 0) scale[row] = safe / 60.0f;
  } else {
    const int row = blockIdx.x - NDIM;
    const float4* xr = (const float4*)(x + (size_t)row * KDIM);
    float4 v[4];
    float am = 0.f;
#pragma unroll
    for (int i = 0; i < 4; ++i) {
      v[i] = xr[t + 256 * i];
      am = fmaxf(am, fmaxf(fmaxf(fabsf(v[i].x), fabsf(v[i].y)),
                           fmaxf(fabsf(v[i].z), fabsf(v[i].w))));
    }
#pragma unroll
    for (int m = 32; m >= 1; m >>= 1) am = fmaxf(am, __shfl_xor(am, m, 64));
    if ((t & 63) == 0) wred[t >> 6] = am;
    __syncthreads();
    const float amax =
        fmaxf(fmaxf(fmaxf(wred[0], wred[1]), fmaxf(wred[2], wred[3])), 1e-20f);
    const float r = 127.0f / amax;
    unsigned* qr = qx + (size_t)row * (KDIM / 4);
#pragma unroll
    for (int i = 0; i < 4; ++i) {
      float q0 = fminf(fmaxf(rintf(v[i].x * r), -127.f), 127.f);
      float q1 = fminf(fmaxf(rintf(v[i].y * r), -127.f), 127.f);
      float q2 = fminf(fmaxf(rintf(v[i].z * r), -127.f), 127.f);
      float q3 = fminf(fmaxf(rintf(v[i].w * r), -127.f), 127.f);
      qr[t + 256 * i] = pack4(q0, q1, q2, q3);
    }
    if (t == 0) sx[row] = amax / 127.0f;
  }
}

// --- K2: C[m,n] = sx[m]*scale[n]*dot_i8(A[m,:],B[n,:]) + bias[n] ---
// Block tile 128(M) x 256(N), BK=64, double-buffered; 4 waves each 64x128.

// stage tile kt into buffer nb: A 2 issues (64 rows each), B 4 issues
#define STAGE_TILE(nb, kt)                                                 \
  do {                                                                     \
    const char* _ga = gA0 + (kt) * 64;                                     \
    const char* _gb = gB0 + (kt) * 64;                                     \
    async_copy16(_ga, &sA[nb][tid * 16]);                                  \
    async_copy16(_ga + (size_t)64 * KDIM, &sA[nb][4096 + tid * 16]);       \
    async_copy16(_gb, &sB[nb][tid * 16]);                                  \
    async_copy16(_gb + (size_t)64 * KDIM, &sB[nb][4096 + tid * 16]);       \
    async_copy16(_gb + (size_t)128 * KDIM, &sB[nb][8192 + tid * 16]);      \
    async_copy16(_gb + (size_t)192 * KDIM, &sB[nb][12288 + tid * 16]);     \
  } while (0)

#define COMPUTE(cb)                                                        \
  do {                                                                     \
    int32x4 af[4], bg[8];                                                  \
    _Pragma("unroll") for (int i = 0; i < 4; ++i)                          \
        af[i] = *(const int32x4*)&sA[cb][(wm + i * 16 + fr) * 64 + qs];    \
    _Pragma("unroll") for (int j = 0; j < 8; ++j)                          \
        bg[j] = *(const int32x4*)&sB[cb][(wn + j * 16 + fr) * 64 + qs];    \
    __builtin_amdgcn_s_setprio(1);                                         \
    _Pragma("unroll") for (int i = 0; i < 4; ++i)                          \
    _Pragma("unroll") for (int j = 0; j < 8; ++j)                          \
        acc[i][j] = __builtin_amdgcn_mfma_i32_16x16x64_i8(af[i], bg[j],    \
                                                          acc[i][j], 0, 0, 0); \
    __builtin_amdgcn_s_setprio(0);                                         \
  } while (0)

__global__ __launch_bounds__(256, 2) void gemm_i8(const char* __restrict__ A,
                                                  const char* __restrict__ B,
                                                  const float* __restrict__ sx,
                                                  const float* __restrict__ scale,
                                                  const float* __restrict__ bias,
                                                  float* __restrict__ C) {
  __shared__ __align__(16) char sA[2][8192];   // 128 rows x 64 B, x2 = 16 KB
  __shared__ __align__(16) char sB[2][16384];  // 256 rows x 64 B, x2 = 32 KB
  const int tid = threadIdx.x;
  const int m0 = blockIdx.y * 128;
  const int n0 = blockIdx.x * 256;

  // staging: thread t -> (row = t>>2 [+64k per issue], chunk = t&3);
  // source-swizzled chunk: (t&3) ^ ((row>>1)&3); 64k row steps don't change it
  const int srow = tid >> 2;  // 0..63
  const int c4s = (tid & 3) ^ ((srow >> 1) & 3);
  const char* gA0 = A + (size_t)(m0 + srow) * KDIM + c4s * 16;
  const char* gB0 = B + (size_t)(n0 + srow) * KDIM + c4s * 16;

  const int lane = tid & 63;
  const int wid = tid >> 6;
  const int wm = (wid & 1) * 64;    // wave M offset: 0 / 64
  const int wn = (wid >> 1) * 128;  // wave N offset: 0 / 128
  const int fr = lane & 15;         // A: m, B: n within fragment
  const int q = lane >> 4;          // k-quad (16B chunk within 64B row)
  const int qs = (q ^ ((fr >> 1) & 3)) * 16;  // swizzled chunk byte offset

  int32x4 acc[4][8] = {};

  // prologue: tile 0 -> buf0, drain, barrier
  STAGE_TILE(0, 0);
  __syncthreads();

  for (int it = 0; it < 32; ++it) {  // 2 K-steps per iter, 64 total
    // issue next-tile loads FIRST; compute; drain+barrier LAST (latency
    // hides under the 32 MFMAs). One barrier per K-step.
    STAGE_TILE(1, 2 * it + 1);
    COMPUTE(0);
    __syncthreads();
    STAGE_TILE(0, (2 * it + 2) & 63);  // wrap: last stage re-reads tile 0,
    COMPUTE(1);                        // never consumed (uniform code path)
    __syncthreads();
  }

  // epilogue: C/D layout col = lane&15, row = quad*4 + reg (verified R2/R3)
  float scl[8], bs[8];
#pragma unroll
  for (int j = 0; j < 8; ++j) {
    const int n = n0 + wn + j * 16 + fr;
    scl[j] = scale[n];
    bs[j] = bias[n];
  }
  const int mrow = q * 4;
#pragma unroll
  for (int i = 0; i < 4; ++i) {
#pragma unroll
    for (int r = 0; r < 4; ++r) {
      const size_t m = (size_t)(m0 + wm + i * 16 + mrow + r);
      const float sxm = sx[m];
      float* crow = C + m * NDIM + (n0 + wn + fr);
#pragma unroll
      for (int j = 0; j < 8; ++j)
        crow[j * 16] = (float)acc[i][j][r] * (sxm * scl[j]) + bs[j];
    }
  }
}

extern "C" void kernel_launch(void* const* d_in, const int* in_sizes, int n_in,
                              void* d_out, int out_size, void* d_ws, size_t ws_size,
                              hipStream_t stream) {
  (void)in_sizes; (void)n_in; (void)out_size; (void)ws_size;
  const float* x = (const float*)d_in[0];     // [8192, 4096] fp32
  const float* w = (const float*)d_in[1];     // [4096, 4096] fp32
  const float* bias = (const float*)d_in[2];  // [4096] fp32
  float* out = (float*)d_out;                 // [8192, 4096] fp32

  char* ws = (char*)d_ws;
  char* qx = ws;                                           // 32 MB int8
  char* qw = ws + (size_t)33554432;                        // 16 MB int8
  float* sx = (float*)(ws + (size_t)50331648);             // 32 KB
  float* scale = (float*)(ws + (size_t)50331648 + 65536);  // 16 KB

  quantize_all<<<NDIM + MDIM, 256, 0, stream>>>(w, x, (unsigned*)qw,
                                                (unsigned*)qx, scale, sx);
  dim3 grid(NDIM / 256, MDIM / 128);  // (16, 64)
  gemm_i8<<<grid, 256, 0, stream>>>(qx, qw, sx, scale, bias, out);
}

// Round 3
// 382.463 us; speedup vs baseline: 1.0541x; 1.0541x over previous
//
#include <hip/hip_runtime.h>
#include <hip/hip_bf16.h>

// ScalarQLinear via int8 MFMA, round 8:
//   R6/R7 post-mortem: both pipelined-gemm rewrites regressed (143/159 vs
//   R5's 127). R5's acc[4][8]=128 AGPR + 96 VGPR caps residency at 2
//   blocks/CU; schedule surgery can't add overlap beyond what those 2
//   blocks already give, and BK=64 staging halved coalescing (2234->1828
//   GB/s). ALSO: non-gemm time is stable ~245us across rounds (quantize +
//   harness reset) -- gemm is only ~1/3 of wall clock.
//   R8: (1) gemm reverted byte-exact to the measured-127us R5 kernel.
//       (2) quantize_all: numerics-identical grid-stride (2048 blocks = 8/CU,
//           6 rows each) + one-row prefetch pipeline (next row's loads issue
//           before current row's reduce/quant/store -> HBM latency hidden).
//           Per-row thread mapping and every fp expression unchanged.
//   This doubles as a probe: total unchanged => quantize small, residual is
//   harness overhead; total drops => quantize was latency-bound.

typedef int int32x4 __attribute__((ext_vector_type(4)));

#define MDIM 8192
#define NDIM 4096
#define KDIM 4096

__device__ __forceinline__ void async_copy16(const void* g, void* l) {
  __builtin_amdgcn_global_load_lds(
      (const __attribute__((address_space(1))) void*)g,
      (__attribute__((address_space(3))) void*)l, 16, 0, 0);
}

__device__ __forceinline__ unsigned pack4(float a, float b, float c, float d) {
  return ((unsigned)((int)a & 0xff)) | ((unsigned)((int)b & 0xff) << 8) |
         ((unsigned)((int)c & 0xff) << 16) | ((unsigned)((int)d & 0xff) << 24);
}

// --- K1: fused quantizers, grid-stride pipelined. Tasks [0,4096): w rows;
// [4096,12288): x rows. 2048 blocks x 6 tasks, per-row numerics identical
// to the single-task version (same thread mapping, same add/max order). ---
__global__ __launch_bounds__(256) void quantize_all(
    const float* __restrict__ w, const float* __restrict__ x,
    unsigned* __restrict__ qw, unsigned* __restrict__ qx,
    float* __restrict__ scale, float* __restrict__ sx) {
  const int t = threadIdx.x;
  __shared__ float wred[4];

  int task = blockIdx.x;
  {
    const float4* rp = (task < NDIM)
        ? (const float4*)(w + (size_t)task * KDIM)
        : (const float4*)(x + (size_t)(task - NDIM) * KDIM);
#pragma unroll
    for (int i = 0; i < 4; ++i) {
      // nothing yet; loads issued below into v
    }
  }
  float4 v[4];
  {
    const float4* rp = (task < NDIM)
        ? (const float4*)(w + (size_t)task * KDIM)
        : (const float4*)(x + (size_t)(task - NDIM) * KDIM);
#pragma unroll
    for (int i = 0; i < 4; ++i) v[i] = rp[t + 256 * i];
  }

  while (true) {
    const int next = task + 2048;
    float4 vn[4];
    if (next < NDIM + MDIM) {
      const float4* np = (next < NDIM)
          ? (const float4*)(w + (size_t)next * KDIM)
          : (const float4*)(x + (size_t)(next - NDIM) * KDIM);
#pragma unroll
      for (int i = 0; i < 4; ++i) vn[i] = np[t + 256 * i];
    }

    if (task < NDIM) {
      const int row = task;
      float ss = 0.f;
#pragma unroll
      for (int i = 0; i < 4; ++i)
        ss += v[i].x * v[i].x + v[i].y * v[i].y + v[i].z * v[i].z + v[i].w * v[i].w;
#pragma unroll
      for (int m = 32; m >= 1; m >>= 1) ss += __shfl_xor(ss, m, 64);
      if ((t & 63) == 0) wred[t >> 6] = ss;
      __syncthreads();
      const float safe = fmaxf(sqrtf(wred[0] + wred[1] + wred[2] + wred[3]), 1e-8f);
      unsigned* qr = qw + (size_t)row * (KDIM / 4);
#pragma unroll
      for (int i = 0; i < 4; ++i) {
        float q0 = fminf(fmaxf(rintf(v[i].x / safe * 60.0f), -8.f), 7.f);
        float q1 = fminf(fmaxf(rintf(v[i].y / safe * 60.0f), -8.f), 7.f);
        float q2 = fminf(fmaxf(rintf(v[i].z / safe * 60.0f), -8.f), 7.f);
        float q3 = fminf(fmaxf(rintf(v[i].w / safe * 60.0f), -8.f), 7.f);
        qr[t + 256 * i] = pack4(q0, q1, q2, q3);
      }
      if (t == 0) scale[row] = safe / 60.0f;
    } else {
      const int row = task - NDIM;
      float am = 0.f;
#pragma unroll
      for (int i = 0; i < 4; ++i)
        am = fmaxf(am, fmaxf(fmaxf(fabsf(v[i].x), fabsf(v[i].y)),
                             fmaxf(fabsf(v[i].z), fabsf(v[i].w))));
#pragma unroll
      for (int m = 32; m >= 1; m >>= 1) am = fmaxf(am, __shfl_xor(am, m, 64));
      if ((t & 63) == 0) wred[t >> 6] = am;
      __syncthreads();
      const float amax =
          fmaxf(fmaxf(fmaxf(wred[0], wred[1]), fmaxf(wred[2], wred[3])), 1e-20f);
      const float r = 127.0f / amax;
      unsigned* qr = qx + (size_t)row * (KDIM / 4);
#pragma unroll
      for (int i = 0; i < 4; ++i) {
        float q0 = fminf(fmaxf(rintf(v[i].x * r), -127.f), 127.f);
        float q1 = fminf(fmaxf(rintf(v[i].y * r), -127.f), 127.f);
        float q2 = fminf(fmaxf(rintf(v[i].z * r), -127.f), 127.f);
        float q3 = fminf(fmaxf(rintf(v[i].w * r), -127.f), 127.f);
        qr[t + 256 * i] = pack4(q0, q1, q2, q3);
      }
      if (t == 0) sx[row] = amax / 127.0f;
    }
    __syncthreads();  // wred reused next task
    if (next >= NDIM + MDIM) break;
    task = next;
#pragma unroll
    for (int i = 0; i < 4; ++i) v[i] = vn[i];
  }
}

// --- K2: C[m,n] = sx[m]*scale[n]*dot_i8(A[m,:],B[n,:]) + bias[n] ---
// Block tile 128(M) x 256(N), BK=128; 4 waves each 64x128 (acc 4x8).
// Byte-exact revert to the R5 kernel measured at 127us / MfmaUtil 46%.
__global__ __launch_bounds__(256, 2) void gemm_i8(const char* __restrict__ A,
                                                  const char* __restrict__ B,
                                                  const float* __restrict__ sx,
                                                  const float* __restrict__ scale,
                                                  const float* __restrict__ bias,
                                                  float* __restrict__ C) {
  __shared__ __align__(16) char sA[128 * 128];  // 16 KB (x tile)
  __shared__ __align__(16) char sB[256 * 128];  // 32 KB (w tile)
  const int tid = threadIdx.x;
  const int m0 = blockIdx.y * 128;
  const int n0 = blockIdx.x * 256;

  // staging: lane tid -> LDS slot (row = issue*32 + tid>>3, chunk = tid&7);
  // phys_chunk = logical_chunk ^ (row&7) applied at the SOURCE.
  const int r0 = tid >> 3;                              // 0..31
  const int c16 = ((tid & 7) ^ ((tid >> 3) & 7)) * 16;  // swizzled source col
  const char* gA = A + (size_t)(m0 + r0) * KDIM + c16;
  const char* gB = B + (size_t)(n0 + r0) * KDIM + c16;
  char* lA = sA + tid * 16;
  char* lB = sB + tid * 16;

  const int lane = tid & 63;
  const int wid = tid >> 6;
  const int wm = (wid & 1) * 64;    // wave M offset: 0 / 64
  const int wn = (wid >> 1) * 128;  // wave N offset: 0 / 128
  const int fr = lane & 15;  // A: m, B: n
  const int q = lane >> 4;   // k-quad
  const int sw = fr & 7;
  const int ph0 = ((q) ^ sw) * 16;      // phys chunk offset, k-half 0
  const int ph1 = ((4 + q) ^ sw) * 16;  // phys chunk offset, k-half 1

  int32x4 acc[4][8] = {};

  for (int kt = 0; kt < KDIM / 128; ++kt) {  // 32 iterations
    __syncthreads();  // prior-iter LDS reads done before overwrite
#pragma unroll
    for (int i = 0; i < 4; ++i)
      async_copy16(gA + (size_t)(32 * i) * KDIM, lA + i * 4096);
#pragma unroll
    for (int i = 0; i < 8; ++i)
      async_copy16(gB + (size_t)(32 * i) * KDIM, lB + i * 4096);
    __syncthreads();  // vmcnt(0) drain + barrier
    gA += 128; gB += 128;

#pragma unroll
    for (int h = 0; h < 2; ++h) {
      const int ph = h ? ph1 : ph0;
      int32x4 af[4], bg[8];
#pragma unroll
      for (int i = 0; i < 4; ++i)
        af[i] = *(const int32x4*)&sA[(wm + i * 16 + fr) * 128 + ph];
#pragma unroll
      for (int j = 0; j < 8; ++j)
        bg[j] = *(const int32x4*)&sB[(wn + j * 16 + fr) * 128 + ph];
#pragma unroll
      for (int i = 0; i < 4; ++i)
#pragma unroll
        for (int j = 0; j < 8; ++j)
          acc[i][j] =
              __builtin_amdgcn_mfma_i32_16x16x64_i8(af[i], bg[j], acc[i][j], 0, 0, 0);
    }
  }

  // epilogue: C/D layout col = lane&15, row = quad*4 + reg (shape-determined)
  float scl[8], bs[8];
#pragma unroll
  for (int j = 0; j < 8; ++j) {
    const int n = n0 + wn + j * 16 + fr;
    scl[j] = scale[n];
    bs[j] = bias[n];
  }
  const int mrow = q * 4;
#pragma unroll
  for (int i = 0; i < 4; ++i) {
#pragma unroll
    for (int r = 0; r < 4; ++r) {
      const size_t m = (size_t)(m0 + wm + i * 16 + mrow + r);
      const float sxm = sx[m];
      float* crow = C + m * NDIM + (n0 + wn + fr);
#pragma unroll
      for (int j = 0; j < 8; ++j)
        crow[j * 16] = (float)acc[i][j][r] * (sxm * scl[j]) + bs[j];
    }
  }
}

extern "C" void kernel_launch(void* const* d_in, const int* in_sizes, int n_in,
                              void* d_out, int out_size, void* d_ws, size_t ws_size,
                              hipStream_t stream) {
  (void)in_sizes; (void)n_in; (void)out_size; (void)ws_size;
  const float* x = (const float*)d_in[0];     // [8192, 4096] fp32
  const float* w = (const float*)d_in[1];     // [4096, 4096] fp32
  const float* bias = (const float*)d_in[2];  // [4096] fp32
  float* out = (float*)d_out;                 // [8192, 4096] fp32

  char* ws = (char*)d_ws;
  char* qx = ws;                                           // 32 MB int8
  char* qw = ws + (size_t)33554432;                        // 16 MB int8
  float* sx = (float*)(ws + (size_t)50331648);             // 32 KB
  float* scale = (float*)(ws + (size_t)50331648 + 65536);  // 16 KB

  quantize_all<<<2048, 256, 0, stream>>>(w, x, (unsigned*)qw,
                                         (unsigned*)qx, scale, sx);
  dim3 grid(NDIM / 256, MDIM / 128);  // (16, 64)
  gemm_i8<<<grid, 256, 0, stream>>>(qx, qw, sx, scale, bias, out);
}